// Round 8
// baseline (555.109 us; speedup 1.0000x reference)
//
#include <hip/hip_runtime.h>
#include <hip/hip_bf16.h>
#include <stdint.h>

#define N_NODES 50000
#define N_EDGES 800000
#define D_IN 128
#define D_HID 256
#define D_OUT 128
#define LAYERS 3

// Coarse buckets for the two-level CSR build: 64 dst-nodes per bucket.
#define BUCKET_SHIFT 6
#define NB 782            // ceil(50000/64)

typedef __attribute__((ext_vector_type(8))) short bf16x8;   // 8 bf16 = 4 VGPRs (MFMA A/B frag)
typedef __attribute__((ext_vector_type(4))) float f32x4;    // MFMA C/D frag
typedef __attribute__((ext_vector_type(4))) unsigned short us4;
typedef __attribute__((ext_vector_type(8))) unsigned short us8;

static __device__ __forceinline__ unsigned short f2bf(float f) {
  union { float f; unsigned int u; } v; v.f = f;
  unsigned int r = v.u + 0x7fff + ((v.u >> 16) & 1);   // RNE
  return (unsigned short)(r >> 16);
}
static __device__ __forceinline__ float bf2f(unsigned short u) {
  union { unsigned int u; float f; } v; v.u = ((unsigned int)u) << 16;
  return v.f;
}

// ---------------------------------------------------------------------------
// Bucket histogram: LDS pre-aggregation (196 blocks x 4096 edges) ->
// 196*782 global atomics instead of 800K.
// ---------------------------------------------------------------------------
__global__ __launch_bounds__(256) void bhist_kernel(
    const int* __restrict__ dst, int* __restrict__ bcnt) {
  __shared__ int h[NB];
  for (int i = threadIdx.x; i < NB; i += 256) h[i] = 0;
  __syncthreads();
  const int base = blockIdx.x * 4096;
#pragma unroll
  for (int k = 0; k < 16; ++k) {
    int e = base + k * 256 + threadIdx.x;
    if (e < N_EDGES) atomicAdd(&h[dst[e] >> BUCKET_SHIFT], 1);
  }
  __syncthreads();
  for (int i = threadIdx.x; i < NB; i += 256)
    if (h[i]) atomicAdd(&bcnt[i], h[i]);
}

// ---------------------------------------------------------------------------
// Single-block scan of 782 bucket counts -> bucket bases + bin cursors.
// Also sets rowptr[N_NODES] = N_EDGES.
// ---------------------------------------------------------------------------
__global__ __launch_bounds__(1024) void bscan_kernel(
    const int* __restrict__ bcnt, int* __restrict__ bbase,
    int* __restrict__ bcur, int* __restrict__ rowptr) {
  __shared__ int buf[1024];
  const int tid = threadIdx.x;
  int v = (tid < NB) ? bcnt[tid] : 0;
  buf[tid] = v;
  __syncthreads();
  for (int off = 1; off < 1024; off <<= 1) {
    int add = (tid >= off) ? buf[tid - off] : 0;
    __syncthreads();
    buf[tid] += add;
    __syncthreads();
  }
  if (tid < NB) {
    int e0 = buf[tid] - v;     // exclusive
    bbase[tid] = e0;
    bcur[tid] = e0;
  }
  if (tid == 0) { bbase[NB] = N_EDGES; rowptr[N_NODES] = N_EDGES; }
}

// ---------------------------------------------------------------------------
// Bin: scatter packed (local_dst<<16 | src) into per-bucket staged regions.
// Write working set = 782 hot lines (vs 50000 cold regions) -> low write amp.
// ---------------------------------------------------------------------------
__global__ __launch_bounds__(256) void bin_kernel(
    const int* __restrict__ src, const int* __restrict__ dst,
    int* __restrict__ bcur, unsigned int* __restrict__ staged) {
  int e = blockIdx.x * 256 + threadIdx.x;
  if (e >= N_EDGES) return;
  int d = dst[e];
  int b = d >> BUCKET_SHIFT;
  int pos = atomicAdd(&bcur[b], 1);
  staged[pos] = ((unsigned int)(d & 63) << 16) | (unsigned int)src[e];
}

// ---------------------------------------------------------------------------
// Per-bucket counting sort (no capacity limit: two sweeps over the staged
// list).  Produces exact fine rowptr + contiguous ushort eidx writes.
// ---------------------------------------------------------------------------
__global__ __launch_bounds__(256) void bsort_kernel(
    const unsigned int* __restrict__ staged, const int* __restrict__ bbase,
    int* __restrict__ rowptr, unsigned short* __restrict__ eidx) {
  __shared__ int cnt[64];
  __shared__ int pre[64];
  __shared__ int cur[64];
  const int tid = threadIdx.x;
  const int b = blockIdx.x;
  const int j0 = bbase[b], j1 = bbase[b + 1];
  if (tid < 64) cnt[tid] = 0;
  __syncthreads();
  // sweep 1: local-dst histogram
  for (int j = j0 + tid; j < j1; j += 256)
    atomicAdd(&cnt[(staged[j] >> 16) & 63], 1);
  __syncthreads();
  // wave-0 exclusive scan of 64 counters
  if (tid < 64) {
    int c = cnt[tid];
    int v = c;
    for (int off = 1; off < 64; off <<= 1) {
      int n = __shfl_up(v, off);
      if (tid >= off) v += n;
    }
    int ex = v - c;            // exclusive prefix
    pre[tid] = ex;
    cur[tid] = ex;
    int node = (b << BUCKET_SHIFT) + tid;
    if (node < N_NODES) rowptr[node] = j0 + ex;
  }
  __syncthreads();
  // sweep 2: place src into eidx (contiguous 2-4KB region per bucket)
  for (int j = j0 + tid; j < j1; j += 256) {
    unsigned int p = staged[j];
    int ld = (p >> 16) & 63;
    int rel = atomicAdd(&cur[ld], 1);
    eidx[j0 + rel] = (unsigned short)(p & 0xffffu);
  }
}

// ---------------------------------------------------------------------------
// Convert x0 (f32) -> bf16.  6.4M elems, float4 -> us4.
// ---------------------------------------------------------------------------
__global__ __launch_bounds__(256) void convert_x(
    const float* __restrict__ x, unsigned short* __restrict__ xb) {
  int i = blockIdx.x * 256 + threadIdx.x;        // float4 index
  if (i >= N_NODES * D_IN / 4) return;
  float4 v = ((const float4*)x)[i];
  us4 p = { f2bf(v.x), f2bf(v.y), f2bf(v.z), f2bf(v.w) };
  ((us4*)xb)[i] = p;
}

// ---------------------------------------------------------------------------
// Aggregation: aggb[n] = xb[n] + sum_{j in CSR[n]} xb[eidx[j]].  No atomics.
// One wave per node; lane owns features 2t, 2t+1 (256B coalesced row reads).
// 4-edge unroll for >=8 outstanding loads; f32 accumulation.
// ---------------------------------------------------------------------------
__global__ __launch_bounds__(256) void agg_kernel(
    const unsigned short* __restrict__ xb, const int* __restrict__ rowptr,
    const unsigned short* __restrict__ eidx, unsigned short* __restrict__ aggb) {
  int n = blockIdx.x * 4 + (threadIdx.x >> 6);
  if (n >= N_NODES) return;
  int t = threadIdx.x & 63;
  const size_t tt = (size_t)t * 2;
  ushort2 own = *(const ushort2*)&xb[(size_t)n * D_IN + tt];
  float a0 = bf2f(own.x), a1 = bf2f(own.y);
  float c0 = 0.f, c1 = 0.f;
  int j = rowptr[n];
  const int end = rowptr[n + 1];
  for (; j + 3 < end; j += 4) {
    int s0 = eidx[j], s1 = eidx[j + 1], s2 = eidx[j + 2], s3 = eidx[j + 3];
    ushort2 v0 = *(const ushort2*)&xb[(size_t)s0 * D_IN + tt];
    ushort2 v1 = *(const ushort2*)&xb[(size_t)s1 * D_IN + tt];
    ushort2 v2 = *(const ushort2*)&xb[(size_t)s2 * D_IN + tt];
    ushort2 v3 = *(const ushort2*)&xb[(size_t)s3 * D_IN + tt];
    a0 += bf2f(v0.x) + bf2f(v1.x);
    a1 += bf2f(v0.y) + bf2f(v1.y);
    c0 += bf2f(v2.x) + bf2f(v3.x);
    c1 += bf2f(v2.y) + bf2f(v3.y);
  }
  for (; j < end; ++j) {
    int s = eidx[j];
    ushort2 v = *(const ushort2*)&xb[(size_t)s * D_IN + tt];
    a0 += bf2f(v.x);
    a1 += bf2f(v.y);
  }
  a0 += c0; a1 += c1;
  ushort2 r = { f2bf(a0), f2bf(a1) };
  *(ushort2*)&aggb[(size_t)n * D_IN + tt] = r;
}

// ---------------------------------------------------------------------------
// Convert W1 [L][K=128][N=256] and W2 [L][K=256][N=128] (f32) to bf16,
// TRANSPOSED to [L][N][K] so MFMA B-fragments are 16B-contiguous loads.
// ---------------------------------------------------------------------------
__global__ __launch_bounds__(256) void convert_weights(
    const float* __restrict__ W1, const float* __restrict__ W2,
    unsigned short* __restrict__ w1bf, unsigned short* __restrict__ w2bf) {
  int idx = blockIdx.x * 256 + threadIdx.x;
  const int per = LAYERS * D_IN * D_HID;   // 98304 (same count for both)
  if (idx < per) {
    int l = idx / (D_IN * D_HID);
    int r = idx % (D_IN * D_HID);
    int n = r / D_IN;        // 0..255
    int k = r % D_IN;        // 0..127
    w1bf[idx] = f2bf(W1[(size_t)l * D_IN * D_HID + (size_t)k * D_HID + n]);
  } else {
    int j = idx - per;
    if (j < LAYERS * D_HID * D_OUT) {
      int l = j / (D_HID * D_OUT);
      int r = j % (D_HID * D_OUT);
      int n = r / D_HID;     // 0..127
      int k = r % D_HID;     // 0..255
      w2bf[j] = f2bf(W2[(size_t)l * D_HID * D_OUT + (size_t)k * D_OUT + n]);
    }
  }
}

// ---------------------------------------------------------------------------
// MLP layer 1: h = relu(aggb @ W1 + b1).  M=50000, N=256, K=128, bf16 in.
// Block = 256 thr (4 waves), tile 64x256; wave w handles cols [w*64, w*64+64).
// ---------------------------------------------------------------------------
#define LDA1 136
__global__ __launch_bounds__(256) void mlp1_kernel(
    const unsigned short* __restrict__ aggb, const unsigned short* __restrict__ w1,
    const float* __restrict__ b1, unsigned short* __restrict__ h) {
  __shared__ unsigned short As[64 * LDA1];
  const int tid = threadIdx.x;
  const int block_row = blockIdx.x * 64;

  // Stage A: 64 rows x 128 bf16 = 1024 us8 chunks (16 per row).
  for (int k = 0; k < 4; ++k) {
    int j = tid + k * 256;
    int row = j >> 4;
    int c8 = j & 15;
    int node = block_row + row;
    if (node >= N_NODES) node = N_NODES - 1;   // clamp; garbage rows never stored
    us8 v = *(const us8*)&aggb[(size_t)node * D_IN + c8 * 8];
    *(us8*)&As[row * LDA1 + c8 * 8] = v;
  }
  __syncthreads();

  const int wave = tid >> 6;
  const int lane = tid & 63;
  const int lo16 = lane & 15;
  const int hi4  = lane >> 4;
  const int ncol0 = wave * 64;

  f32x4 acc[4][4] = {};
  for (int ks = 0; ks < 4; ++ks) {
    const int koff = ks * 32 + hi4 * 8;
    bf16x8 a[4], b[4];
#pragma unroll
    for (int m = 0; m < 4; ++m)
      a[m] = *(const bf16x8*)&As[(m * 16 + lo16) * LDA1 + koff];
#pragma unroll
    for (int n = 0; n < 4; ++n)
      b[n] = *(const bf16x8*)&w1[(size_t)(ncol0 + n * 16 + lo16) * D_IN + koff];
#pragma unroll
    for (int m = 0; m < 4; ++m)
#pragma unroll
      for (int n = 0; n < 4; ++n)
        acc[m][n] = __builtin_amdgcn_mfma_f32_16x16x32_bf16(a[m], b[n], acc[m][n], 0, 0, 0);
  }

#pragma unroll
  for (int n = 0; n < 4; ++n) {
    int col = ncol0 + n * 16 + lo16;
    float bias = b1[col];
#pragma unroll
    for (int m = 0; m < 4; ++m) {
#pragma unroll
      for (int r = 0; r < 4; ++r) {
        int node = block_row + m * 16 + hi4 * 4 + r;
        if (node < N_NODES) {
          float v = acc[m][n][r] + bias;
          v = v > 0.f ? v : 0.f;
          h[(size_t)node * D_HID + col] = f2bf(v);
        }
      }
    }
  }
}

// ---------------------------------------------------------------------------
// MLP layer 2: out = h @ W2 + b2.  M=50000, N=128, K=256.
// FINAL=true -> f32 out; else bf16 xbuf (feeds next layer's gather).
// ---------------------------------------------------------------------------
#define LDA2 264
template <bool FINAL>
__global__ __launch_bounds__(256) void mlp2_kernel(
    const unsigned short* __restrict__ h, const unsigned short* __restrict__ w2,
    const float* __restrict__ b2, float* __restrict__ outf,
    unsigned short* __restrict__ outb) {
  __shared__ unsigned short As[64 * LDA2];
  const int tid = threadIdx.x;
  const int block_row = blockIdx.x * 64;

  // Stage A: 64 rows x 256 bf16.  2048 us8 (16B) loads, coalesced.
  for (int k = 0; k < 8; ++k) {
    int j = tid + k * 256;
    int row = j >> 5;
    int c8 = j & 31;
    int node = block_row + row;
    if (node >= N_NODES) node = N_NODES - 1;
    us8 v = *(const us8*)&h[(size_t)node * D_HID + c8 * 8];
    *(us8*)&As[row * LDA2 + c8 * 8] = v;
  }
  __syncthreads();

  const int wave = tid >> 6;
  const int lane = tid & 63;
  const int lo16 = lane & 15;
  const int hi4  = lane >> 4;
  const int ncol0 = wave * 32;

  f32x4 acc[4][2] = {};
  for (int ks = 0; ks < 8; ++ks) {
    const int koff = ks * 32 + hi4 * 8;
    bf16x8 a[4], b[2];
#pragma unroll
    for (int m = 0; m < 4; ++m)
      a[m] = *(const bf16x8*)&As[(m * 16 + lo16) * LDA2 + koff];
#pragma unroll
    for (int n = 0; n < 2; ++n)
      b[n] = *(const bf16x8*)&w2[(size_t)(ncol0 + n * 16 + lo16) * D_HID + koff];
#pragma unroll
    for (int m = 0; m < 4; ++m)
#pragma unroll
      for (int n = 0; n < 2; ++n)
        acc[m][n] = __builtin_amdgcn_mfma_f32_16x16x32_bf16(a[m], b[n], acc[m][n], 0, 0, 0);
  }

#pragma unroll
  for (int n = 0; n < 2; ++n) {
    int col = ncol0 + n * 16 + lo16;
    float bias = b2[col];
#pragma unroll
    for (int m = 0; m < 4; ++m) {
#pragma unroll
      for (int r = 0; r < 4; ++r) {
        int node = block_row + m * 16 + hi4 * 4 + r;
        if (node < N_NODES) {
          float v = acc[m][n][r] + bias;
          if (FINAL) outf[(size_t)node * D_OUT + col] = v;
          else       outb[(size_t)node * D_OUT + col] = f2bf(v);
        }
      }
    }
  }
}

// ---------------------------------------------------------------------------
extern "C" void kernel_launch(void* const* d_in, const int* in_sizes, int n_in,
                              void* d_out, int out_size, void* d_ws, size_t ws_size,
                              hipStream_t stream) {
  const float* x0 = (const float*)d_in[0];
  const float* W1 = (const float*)d_in[1];
  const float* b1 = (const float*)d_in[2];
  const float* W2 = (const float*)d_in[3];
  const float* b2 = (const float*)d_in[4];
  const int* src  = (const int*)d_in[5];
  const int* dst  = (const int*)d_in[6];
  float* out = (float*)d_out;

  char* ws = (char*)d_ws;
  size_t off = 0;
  unsigned short* xb   = (unsigned short*)(ws + off); off += (size_t)N_NODES * D_IN * 2;   // 12.8 MB
  unsigned short* aggb = (unsigned short*)(ws + off); off += (size_t)N_NODES * D_IN * 2;   // 12.8 MB
  unsigned short* hbuf = (unsigned short*)(ws + off); off += (size_t)N_NODES * D_HID * 2;  // 25.6 MB
  unsigned short* xbuf = (unsigned short*)(ws + off); off += (size_t)N_NODES * D_OUT * 2;  // 12.8 MB
  unsigned short* w1bf = (unsigned short*)(ws + off); off += (size_t)LAYERS * D_IN * D_HID * 2;
  unsigned short* w2bf = (unsigned short*)(ws + off); off += (size_t)LAYERS * D_HID * D_OUT * 2;
  int* bcnt   = (int*)(ws + off); off += (size_t)NB * 4;
  int* bbase  = (int*)(ws + off); off += (size_t)(NB + 1) * 4;
  int* bcur   = (int*)(ws + off); off += (size_t)NB * 4;
  int* rowptr = (int*)(ws + off); off += (size_t)(N_NODES + 1) * 4;
  unsigned int* staged = (unsigned int*)(ws + off); off += (size_t)N_EDGES * 4;  // 3.2 MB
  unsigned short* eidx = (unsigned short*)(ws + off); off += (size_t)N_EDGES * 2; // 1.6 MB

  // --- Two-level CSR build (per launch; ws is re-poisoned each call) ---
  hipMemsetAsync(bcnt, 0, (size_t)NB * 4, stream);
  bhist_kernel<<<196, 256, 0, stream>>>(dst, bcnt);
  bscan_kernel<<<1, 1024, 0, stream>>>(bcnt, bbase, bcur, rowptr);
  bin_kernel<<<N_EDGES / 256, 256, 0, stream>>>(src, dst, bcur, staged);
  bsort_kernel<<<NB, 256, 0, stream>>>(staged, bbase, rowptr, eidx);

  convert_x<<<(N_NODES * D_IN / 4 + 255) / 256, 256, 0, stream>>>(x0, xb);
  convert_weights<<<768, 256, 0, stream>>>(W1, W2, w1bf, w2bf);

  const int grid_mlp = (N_NODES + 63) / 64;   // 782
  const int grid_agg = (N_NODES + 3) / 4;     // 12500
  const unsigned short* xcur = xb;
  for (int l = 0; l < LAYERS; ++l) {
    agg_kernel<<<grid_agg, 256, 0, stream>>>(xcur, rowptr, eidx, aggb);
    mlp1_kernel<<<grid_mlp, 256, 0, stream>>>(
        aggb, w1bf + (size_t)l * D_IN * D_HID, b1 + (size_t)l * D_HID, hbuf);
    if (l == LAYERS - 1) {
      mlp2_kernel<true><<<grid_mlp, 256, 0, stream>>>(
          hbuf, w2bf + (size_t)l * D_HID * D_OUT, b2 + (size_t)l * D_OUT, out, nullptr);
    } else {
      mlp2_kernel<false><<<grid_mlp, 256, 0, stream>>>(
          hbuf, w2bf + (size_t)l * D_HID * D_OUT, b2 + (size_t)l * D_OUT, nullptr, xbuf);
    }
    xcur = xbuf;
  }
}

// Round 15
// 430.684 us; speedup vs baseline: 1.2889x; 1.2889x over previous
//
#include <hip/hip_runtime.h>
#include <hip/hip_bf16.h>
#include <stdint.h>

#define N_NODES 50000
#define N_EDGES 800000
#define D_IN 128
#define D_HID 256
#define D_OUT 128
#define LAYERS 3

typedef __attribute__((ext_vector_type(8))) short bf16x8;   // 8 bf16 = 4 VGPRs (MFMA A/B frag)
typedef __attribute__((ext_vector_type(4))) float f32x4;    // MFMA C/D frag
typedef __attribute__((ext_vector_type(4))) unsigned short us4;
typedef __attribute__((ext_vector_type(8))) unsigned short us8;

static __device__ __forceinline__ unsigned short f2bf(float f) {
  union { float f; unsigned int u; } v; v.f = f;
  unsigned int r = v.u + 0x7fff + ((v.u >> 16) & 1);   // RNE
  return (unsigned short)(r >> 16);
}
static __device__ __forceinline__ float bf2f(unsigned short u) {
  union { unsigned int u; float f; } v; v.u = ((unsigned int)u) << 16;
  return v.f;
}

// ---------------------------------------------------------------------------
// CSR build: histogram of dst -> 3-phase multi-block exclusive scan -> fill.
// (R7-measured design: 50000-way cursor spreads atomic contention; bucket
//  variants (R8) collapse onto 782 lines and serialize on contention.)
// ---------------------------------------------------------------------------
__global__ __launch_bounds__(256) void hist_kernel(
    const int* __restrict__ dst, int* __restrict__ deg) {
  int e = blockIdx.x * 256 + threadIdx.x;
  if (e < N_EDGES) atomicAdd(&deg[dst[e]], 1);
}

#define SCAN_BLOCKS 196   // 196*256 = 50176 >= 50000

__global__ __launch_bounds__(256) void scan_a_kernel(
    const int* __restrict__ deg, int* __restrict__ rowptr,
    int* __restrict__ partial) {
  __shared__ int buf[256];
  const int tid = threadIdx.x;
  int gid = blockIdx.x * 256 + tid;
  int v = (gid < N_NODES) ? deg[gid] : 0;
  buf[tid] = v;
  __syncthreads();
  for (int off = 1; off < 256; off <<= 1) {
    int add = (tid >= off) ? buf[tid - off] : 0;
    __syncthreads();
    buf[tid] += add;
    __syncthreads();
  }
  if (gid < N_NODES) rowptr[gid] = buf[tid] - v;   // exclusive, local
  if (tid == 255) partial[blockIdx.x] = buf[255];
}

__global__ __launch_bounds__(256) void scan_b_kernel(int* __restrict__ partial) {
  __shared__ int buf[256];
  const int tid = threadIdx.x;
  int v = (tid < SCAN_BLOCKS) ? partial[tid] : 0;
  buf[tid] = v;
  __syncthreads();
  for (int off = 1; off < 256; off <<= 1) {
    int add = (tid >= off) ? buf[tid - off] : 0;
    __syncthreads();
    buf[tid] += add;
    __syncthreads();
  }
  if (tid < SCAN_BLOCKS) partial[tid] = buf[tid] - v;  // exclusive
}

__global__ __launch_bounds__(256) void scan_c_kernel(
    int* __restrict__ rowptr, const int* __restrict__ partial,
    int* __restrict__ cursor) {
  int gid = blockIdx.x * 256 + threadIdx.x;
  if (gid < N_NODES) {
    int r = rowptr[gid] + partial[blockIdx.x];
    rowptr[gid] = r;
    cursor[gid] = r;
  }
  if (gid == 0) rowptr[N_NODES] = N_EDGES;
}

__global__ __launch_bounds__(256) void fill_kernel(
    const int* __restrict__ src, const int* __restrict__ dst,
    int* __restrict__ cursor, unsigned short* __restrict__ eidx) {
  int e = blockIdx.x * 256 + threadIdx.x;
  if (e >= N_EDGES) return;
  int pos = atomicAdd(&cursor[dst[e]], 1);
  eidx[pos] = (unsigned short)src[e];
}

// ---------------------------------------------------------------------------
// Convert x0 (f32) -> bf16.  6.4M elems, float4 -> us4.
// ---------------------------------------------------------------------------
__global__ __launch_bounds__(256) void convert_x(
    const float* __restrict__ x, unsigned short* __restrict__ xb) {
  int i = blockIdx.x * 256 + threadIdx.x;        // float4 index
  if (i >= N_NODES * D_IN / 4) return;
  float4 v = ((const float4*)x)[i];
  us4 p = { f2bf(v.x), f2bf(v.y), f2bf(v.z), f2bf(v.w) };
  ((us4*)xb)[i] = p;
}

// ---------------------------------------------------------------------------
// Aggregation v2: one wave per node, TWO edges in flight per wave.
// Lane owns 4 features (ushort4, 32 lanes span the 256B row); lo half-wave
// (lanes 0-31) takes even edges, hi half takes odd.  4-edge unroll -> 2
// independent 256B gathers in flight; fold halves with shfl_xor(32) at end.
// ~2.2x fewer wave-instructions than the per-edge version (latency-bound).
// ---------------------------------------------------------------------------
__global__ __launch_bounds__(256) void agg_kernel(
    const unsigned short* __restrict__ xb, const int* __restrict__ rowptr,
    const unsigned short* __restrict__ eidx, unsigned short* __restrict__ aggb) {
  int n = blockIdx.x * 4 + (threadIdx.x >> 6);
  if (n >= N_NODES) return;
  const int lane = threadIdx.x & 63;
  const int half = lane >> 5;          // 0: even edges, 1: odd edges
  const int q = lane & 31;             // feature quad: features q*4..q*4+3
  const size_t fo = (size_t)q * 4;
  us4 own = *(const us4*)&xb[(size_t)n * D_IN + fo];
  float a0, a1, a2, a3;
  if (half == 0) { a0 = bf2f(own[0]); a1 = bf2f(own[1]); a2 = bf2f(own[2]); a3 = bf2f(own[3]); }
  else           { a0 = 0.f; a1 = 0.f; a2 = 0.f; a3 = 0.f; }
  int j = rowptr[n];
  const int end = rowptr[n + 1];
  for (; j + 3 < end; j += 4) {        // 4 edges/iter: 2 per half
    int s0 = eidx[j + half];
    int s1 = eidx[j + 2 + half];
    us4 v0 = *(const us4*)&xb[(size_t)s0 * D_IN + fo];
    us4 v1 = *(const us4*)&xb[(size_t)s1 * D_IN + fo];
    a0 += bf2f(v0[0]) + bf2f(v1[0]);
    a1 += bf2f(v0[1]) + bf2f(v1[1]);
    a2 += bf2f(v0[2]) + bf2f(v1[2]);
    a3 += bf2f(v0[3]) + bf2f(v1[3]);
  }
  for (int jj = j + half; jj < end; jj += 2) {   // tail: 0..3 edges
    int s = eidx[jj];
    us4 v = *(const us4*)&xb[(size_t)s * D_IN + fo];
    a0 += bf2f(v[0]); a1 += bf2f(v[1]); a2 += bf2f(v[2]); a3 += bf2f(v[3]);
  }
  a0 += __shfl_xor(a0, 32);
  a1 += __shfl_xor(a1, 32);
  a2 += __shfl_xor(a2, 32);
  a3 += __shfl_xor(a3, 32);
  if (half == 0) {
    us4 r = { f2bf(a0), f2bf(a1), f2bf(a2), f2bf(a3) };
    *(us4*)&aggb[(size_t)n * D_IN + fo] = r;     // 32 lanes x 8B = 256B row
  }
}

// ---------------------------------------------------------------------------
// Convert W1 [L][K=128][N=256] and W2 [L][K=256][N=128] (f32) to bf16,
// TRANSPOSED to [L][N][K] so MFMA B-fragments are 16B-contiguous loads.
// ---------------------------------------------------------------------------
__global__ __launch_bounds__(256) void convert_weights(
    const float* __restrict__ W1, const float* __restrict__ W2,
    unsigned short* __restrict__ w1bf, unsigned short* __restrict__ w2bf) {
  int idx = blockIdx.x * 256 + threadIdx.x;
  const int per = LAYERS * D_IN * D_HID;   // 98304 (same count for both)
  if (idx < per) {
    int l = idx / (D_IN * D_HID);
    int r = idx % (D_IN * D_HID);
    int n = r / D_IN;        // 0..255
    int k = r % D_IN;        // 0..127
    w1bf[idx] = f2bf(W1[(size_t)l * D_IN * D_HID + (size_t)k * D_HID + n]);
  } else {
    int j = idx - per;
    if (j < LAYERS * D_HID * D_OUT) {
      int l = j / (D_HID * D_OUT);
      int r = j % (D_HID * D_OUT);
      int n = r / D_HID;     // 0..127
      int k = r % D_HID;     // 0..255
      w2bf[j] = f2bf(W2[(size_t)l * D_HID * D_OUT + (size_t)k * D_OUT + n]);
    }
  }
}

// ---------------------------------------------------------------------------
// MLP layer 1: h = relu(aggb @ W1 + b1).  M=50000, N=256, K=128, bf16 in.
// Block = 256 thr (4 waves), tile 64x256; wave w handles cols [w*64, w*64+64).
// ---------------------------------------------------------------------------
#define LDA1 136
__global__ __launch_bounds__(256) void mlp1_kernel(
    const unsigned short* __restrict__ aggb, const unsigned short* __restrict__ w1,
    const float* __restrict__ b1, unsigned short* __restrict__ h) {
  __shared__ unsigned short As[64 * LDA1];
  const int tid = threadIdx.x;
  const int block_row = blockIdx.x * 64;

  // Stage A: 64 rows x 128 bf16 = 1024 us8 chunks (16 per row).
  for (int k = 0; k < 4; ++k) {
    int j = tid + k * 256;
    int row = j >> 4;
    int c8 = j & 15;
    int node = block_row + row;
    if (node >= N_NODES) node = N_NODES - 1;   // clamp; garbage rows never stored
    us8 v = *(const us8*)&aggb[(size_t)node * D_IN + c8 * 8];
    *(us8*)&As[row * LDA1 + c8 * 8] = v;
  }
  __syncthreads();

  const int wave = tid >> 6;
  const int lane = tid & 63;
  const int lo16 = lane & 15;
  const int hi4  = lane >> 4;
  const int ncol0 = wave * 64;

  f32x4 acc[4][4] = {};
  for (int ks = 0; ks < 4; ++ks) {
    const int koff = ks * 32 + hi4 * 8;
    bf16x8 a[4], b[4];
#pragma unroll
    for (int m = 0; m < 4; ++m)
      a[m] = *(const bf16x8*)&As[(m * 16 + lo16) * LDA1 + koff];
#pragma unroll
    for (int n = 0; n < 4; ++n)
      b[n] = *(const bf16x8*)&w1[(size_t)(ncol0 + n * 16 + lo16) * D_IN + koff];
#pragma unroll
    for (int m = 0; m < 4; ++m)
#pragma unroll
      for (int n = 0; n < 4; ++n)
        acc[m][n] = __builtin_amdgcn_mfma_f32_16x16x32_bf16(a[m], b[n], acc[m][n], 0, 0, 0);
  }

#pragma unroll
  for (int n = 0; n < 4; ++n) {
    int col = ncol0 + n * 16 + lo16;
    float bias = b1[col];
#pragma unroll
    for (int m = 0; m < 4; ++m) {
#pragma unroll
      for (int r = 0; r < 4; ++r) {
        int node = block_row + m * 16 + hi4 * 4 + r;
        if (node < N_NODES) {
          float v = acc[m][n][r] + bias;
          v = v > 0.f ? v : 0.f;
          h[(size_t)node * D_HID + col] = f2bf(v);
        }
      }
    }
  }
}

// ---------------------------------------------------------------------------
// MLP layer 2: out = h @ W2 + b2.  M=50000, N=128, K=256.
// FINAL=true -> f32 out; else bf16 xbuf (feeds next layer's gather).
// ---------------------------------------------------------------------------
#define LDA2 264
template <bool FINAL>
__global__ __launch_bounds__(256) void mlp2_kernel(
    const unsigned short* __restrict__ h, const unsigned short* __restrict__ w2,
    const float* __restrict__ b2, float* __restrict__ outf,
    unsigned short* __restrict__ outb) {
  __shared__ unsigned short As[64 * LDA2];
  const int tid = threadIdx.x;
  const int block_row = blockIdx.x * 64;

  // Stage A: 64 rows x 256 bf16.  2048 us8 (16B) loads, coalesced.
  for (int k = 0; k < 8; ++k) {
    int j = tid + k * 256;
    int row = j >> 5;
    int c8 = j & 31;
    int node = block_row + row;
    if (node >= N_NODES) node = N_NODES - 1;
    us8 v = *(const us8*)&h[(size_t)node * D_HID + c8 * 8];
    *(us8*)&As[row * LDA2 + c8 * 8] = v;
  }
  __syncthreads();

  const int wave = tid >> 6;
  const int lane = tid & 63;
  const int lo16 = lane & 15;
  const int hi4  = lane >> 4;
  const int ncol0 = wave * 32;

  f32x4 acc[4][2] = {};
  for (int ks = 0; ks < 8; ++ks) {
    const int koff = ks * 32 + hi4 * 8;
    bf16x8 a[4], b[2];
#pragma unroll
    for (int m = 0; m < 4; ++m)
      a[m] = *(const bf16x8*)&As[(m * 16 + lo16) * LDA2 + koff];
#pragma unroll
    for (int n = 0; n < 2; ++n)
      b[n] = *(const bf16x8*)&w2[(size_t)(ncol0 + n * 16 + lo16) * D_HID + koff];
#pragma unroll
    for (int m = 0; m < 4; ++m)
#pragma unroll
      for (int n = 0; n < 2; ++n)
        acc[m][n] = __builtin_amdgcn_mfma_f32_16x16x32_bf16(a[m], b[n], acc[m][n], 0, 0, 0);
  }

#pragma unroll
  for (int n = 0; n < 2; ++n) {
    int col = ncol0 + n * 16 + lo16;
    float bias = b2[col];
#pragma unroll
    for (int m = 0; m < 4; ++m) {
#pragma unroll
      for (int r = 0; r < 4; ++r) {
        int node = block_row + m * 16 + hi4 * 4 + r;
        if (node < N_NODES) {
          float v = acc[m][n][r] + bias;
          if (FINAL) outf[(size_t)node * D_OUT + col] = v;
          else       outb[(size_t)node * D_OUT + col] = f2bf(v);
        }
      }
    }
  }
}

// ---------------------------------------------------------------------------
extern "C" void kernel_launch(void* const* d_in, const int* in_sizes, int n_in,
                              void* d_out, int out_size, void* d_ws, size_t ws_size,
                              hipStream_t stream) {
  const float* x0 = (const float*)d_in[0];
  const float* W1 = (const float*)d_in[1];
  const float* b1 = (const float*)d_in[2];
  const float* W2 = (const float*)d_in[3];
  const float* b2 = (const float*)d_in[4];
  const int* src  = (const int*)d_in[5];
  const int* dst  = (const int*)d_in[6];
  float* out = (float*)d_out;

  char* ws = (char*)d_ws;
  size_t off = 0;
  unsigned short* xb   = (unsigned short*)(ws + off); off += (size_t)N_NODES * D_IN * 2;   // 12.8 MB
  unsigned short* aggb = (unsigned short*)(ws + off); off += (size_t)N_NODES * D_IN * 2;   // 12.8 MB
  unsigned short* hbuf = (unsigned short*)(ws + off); off += (size_t)N_NODES * D_HID * 2;  // 25.6 MB
  unsigned short* xbuf = (unsigned short*)(ws + off); off += (size_t)N_NODES * D_OUT * 2;  // 12.8 MB
  unsigned short* w1bf = (unsigned short*)(ws + off); off += (size_t)LAYERS * D_IN * D_HID * 2;
  unsigned short* w2bf = (unsigned short*)(ws + off); off += (size_t)LAYERS * D_HID * D_OUT * 2;
  int* deg     = (int*)(ws + off); off += (size_t)(N_NODES + 1) * 4;
  int* rowptr  = (int*)(ws + off); off += (size_t)(N_NODES + 1) * 4;
  int* cursor  = (int*)(ws + off); off += (size_t)(N_NODES + 1) * 4;
  int* partial = (int*)(ws + off); off += (size_t)SCAN_BLOCKS * 4;
  unsigned short* eidx = (unsigned short*)(ws + off); off += (size_t)N_EDGES * 2;  // 1.6 MB

  // --- CSR build (per launch; ws is re-poisoned each call) ---
  hipMemsetAsync(deg, 0, (size_t)N_NODES * 4, stream);
  hist_kernel<<<N_EDGES / 256, 256, 0, stream>>>(dst, deg);
  scan_a_kernel<<<SCAN_BLOCKS, 256, 0, stream>>>(deg, rowptr, partial);
  scan_b_kernel<<<1, 256, 0, stream>>>(partial);
  scan_c_kernel<<<SCAN_BLOCKS, 256, 0, stream>>>(rowptr, partial, cursor);
  fill_kernel<<<N_EDGES / 256, 256, 0, stream>>>(src, dst, cursor, eidx);

  convert_x<<<(N_NODES * D_IN / 4 + 255) / 256, 256, 0, stream>>>(x0, xb);
  convert_weights<<<768, 256, 0, stream>>>(W1, W2, w1bf, w2bf);

  const int grid_mlp = (N_NODES + 63) / 64;   // 782
  const int grid_agg = (N_NODES + 3) / 4;     // 12500
  const unsigned short* xcur = xb;
  for (int l = 0; l < LAYERS; ++l) {
    agg_kernel<<<grid_agg, 256, 0, stream>>>(xcur, rowptr, eidx, aggb);
    mlp1_kernel<<<grid_mlp, 256, 0, stream>>>(
        aggb, w1bf + (size_t)l * D_IN * D_HID, b1 + (size_t)l * D_HID, hbuf);
    if (l == LAYERS - 1) {
      mlp2_kernel<true><<<grid_mlp, 256, 0, stream>>>(
          hbuf, w2bf + (size_t)l * D_HID * D_OUT, b2 + (size_t)l * D_OUT, out, nullptr);
    } else {
      mlp2_kernel<false><<<grid_mlp, 256, 0, stream>>>(
          hbuf, w2bf + (size_t)l * D_HID * D_OUT, b2 + (size_t)l * D_OUT, nullptr, xbuf);
    }
    xcur = xbuf;
  }
}